// Round 7
// baseline (442.811 us; speedup 1.0000x reference)
//
#include <hip/hip_runtime.h>

#define BB 8
#define LL 2048
#define DD 256
// KV image tile = 32 kv rows:
//   K part: 32 rows x 272 u16, 16B chunk c of row rr stored at c^(rr&7)
//   V part: 256 d x 32 kv u16 (aligned, conflict-free at stride 32)
#define KT_U16 8704
#define TILE_U16 16896
#define TILE_B 33792

typedef _Float16 half8 __attribute__((ext_vector_type(8)));
typedef float floatx4 __attribute__((ext_vector_type(4)));
typedef unsigned short ushort8 __attribute__((ext_vector_type(8)));
typedef unsigned short ushort4v __attribute__((ext_vector_type(4)));

__device__ inline unsigned short f2h(float f) {
  _Float16 h = (_Float16)f;
  return __builtin_bit_cast(unsigned short, h);
}
__device__ inline float h2f16(unsigned short v) {
  return (float)__builtin_bit_cast(_Float16, v);
}

__device__ inline void gll(const void* g, void* l) {
  __builtin_amdgcn_global_load_lds(
      (const __attribute__((address_space(1))) unsigned int*)g,
      (__attribute__((address_space(3))) unsigned int*)l, 16, 0, 0);
}

// ---------------------------------------------------------------------------
// Kernel 1: Q/K projection (R2-proven).  Out[l][d] fp16.
// ---------------------------------------------------------------------------
__global__ __launch_bounds__(256) void qk_proj(
    const float* __restrict__ x,
    const float* __restrict__ Wq, const float* __restrict__ Wk,
    unsigned short* __restrict__ Qb, unsigned short* __restrict__ Kb) {
  __shared__ __attribute__((aligned(16))) unsigned short Xs[64 * 264];
  __shared__ __attribute__((aligned(16))) unsigned short Ws[32 * 264];
  const int t = threadIdx.x;
  const int wave = t >> 6, lane = t & 63, quad = lane >> 4, m16 = lane & 15;
  const int r0 = blockIdx.x * 64;
  const float* W = (blockIdx.y == 0) ? Wq : Wk;
  unsigned short* Out = (blockIdx.y == 0) ? Qb : Kb;

  for (int p = 0; p < 16; ++p) {
    int idx = p * 1024 + t * 4;
    int row = idx >> 8, col = idx & 255;
    float4 v = *(const float4*)(x + (size_t)(r0 + row) * DD + col);
    ushort4v h = {f2h(v.x), f2h(v.y), f2h(v.z), f2h(v.w)};
    *(ushort4v*)&Xs[row * 264 + col] = h;
  }
  __syncthreads();

  half8 af[8];
  for (int kb = 0; kb < 8; ++kb)
    af[kb] = __builtin_bit_cast(
        half8, *(const ushort8*)&Xs[(wave * 16 + m16) * 264 + kb * 32 + quad * 8]);

  for (int c = 0; c < 8; ++c) {
    if (c) __syncthreads();
    for (int p = 0; p < 8; ++p) {
      int idx = p * 1024 + t * 4;
      int row = idx >> 8, col = idx & 255;
      float4 v = *(const float4*)(W + (size_t)(c * 32 + row) * DD + col);
      ushort4v h = {f2h(v.x), f2h(v.y), f2h(v.z), f2h(v.w)};
      *(ushort4v*)&Ws[row * 264 + col] = h;
    }
    __syncthreads();
    floatx4 acc[2] = {{0, 0, 0, 0}, {0, 0, 0, 0}};
    for (int n = 0; n < 2; ++n)
      for (int kb = 0; kb < 8; ++kb) {
        half8 bf = __builtin_bit_cast(
            half8,
            *(const ushort8*)&Ws[(n * 16 + m16) * 264 + kb * 32 + quad * 8]);
        acc[n] = __builtin_amdgcn_mfma_f32_16x16x32_f16(af[kb], bf, acc[n], 0, 0, 0);
      }
    for (int n = 0; n < 2; ++n)
      for (int r = 0; r < 4; ++r) {
        int rowg = r0 + wave * 16 + quad * 4 + r;
        int colg = c * 32 + n * 16 + m16;
        Out[(size_t)rowg * DD + colg] = f2h(acc[n][r]);
      }
  }
}

// ---------------------------------------------------------------------------
// Kernel 1b: V projection writing V TRANSPOSED VT[b][d][l] (R2-proven).
// ---------------------------------------------------------------------------
__global__ __launch_bounds__(256) void vproj_t(
    const float* __restrict__ x, const float* __restrict__ Wv,
    unsigned short* __restrict__ VT) {
  __shared__ __attribute__((aligned(16))) unsigned short Xs[64 * 264];
  __shared__ __attribute__((aligned(16))) unsigned short Ws[64 * 264];
  const int t = threadIdx.x;
  const int wave = t >> 6, lane = t & 63, quad = lane >> 4, m16 = lane & 15;
  const int l0 = blockIdx.x * 64;
  const int b = l0 >> 11, lb = l0 & 2047;

  for (int p = 0; p < 16; ++p) {
    int idx = p * 1024 + t * 4;
    int row = idx >> 8, col = idx & 255;
    float4 v = *(const float4*)(x + (size_t)(l0 + row) * DD + col);
    ushort4v h = {f2h(v.x), f2h(v.y), f2h(v.z), f2h(v.w)};
    *(ushort4v*)&Xs[row * 264 + col] = h;
  }
  __syncthreads();

  half8 xf[8];
  for (int kb = 0; kb < 8; ++kb)
    xf[kb] = __builtin_bit_cast(
        half8, *(const ushort8*)&Xs[(wave * 16 + m16) * 264 + kb * 32 + quad * 8]);

  for (int c = 0; c < 4; ++c) {
    if (c) __syncthreads();
    for (int p = 0; p < 16; ++p) {
      int idx = p * 1024 + t * 4;
      int row = idx >> 8, col = idx & 255;
      float4 v = *(const float4*)(Wv + (size_t)(c * 64 + row) * DD + col);
      ushort4v h = {f2h(v.x), f2h(v.y), f2h(v.z), f2h(v.w)};
      *(ushort4v*)&Ws[row * 264 + col] = h;
    }
    __syncthreads();
    for (int mt = 0; mt < 4; ++mt) {
      floatx4 acc = {0, 0, 0, 0};
      for (int kb = 0; kb < 8; ++kb) {
        half8 af = __builtin_bit_cast(
            half8,
            *(const ushort8*)&Ws[(mt * 16 + m16) * 264 + kb * 32 + quad * 8]);
        acc = __builtin_amdgcn_mfma_f32_16x16x32_f16(af, xf[kb], acc, 0, 0, 0);
      }
      int o = c * 64 + mt * 16 + quad * 4;
      int l = lb + wave * 16 + m16;
      for (int r = 0; r < 4; ++r)
        VT[((size_t)(b * DD + o + r)) * LL + l] = f2h(acc[r]);
    }
  }
}

// ---------------------------------------------------------------------------
// Kernel 1c: pack Kb[l][d] -> swizzled K part of KV image.
// ---------------------------------------------------------------------------
__global__ __launch_bounds__(256) void kpack(
    const unsigned short* __restrict__ Kb, unsigned short* __restrict__ KV) {
  const int base = blockIdx.x * 2048 + threadIdx.x;
  for (int it = 0; it < 8; ++it) {
    int id = base + it * 256;  // 524288 chunks: row = l-global, c = d/8
    int row = id >> 5, c = id & 31;
    ushort8 v = *(const ushort8*)(Kb + (size_t)row * DD + c * 8);
    int tile = row >> 5, rr = row & 31;
    *(ushort8*)(KV + (size_t)tile * TILE_U16 + rr * 272 + ((c ^ (rr & 7)) * 8)) = v;
  }
}

// ---------------------------------------------------------------------------
// Kernel 1d: pack VT[b][d][l] -> V part of KV image ([d][32kv] per tile).
// ---------------------------------------------------------------------------
__global__ __launch_bounds__(256) void vpack(
    const unsigned short* __restrict__ VT, unsigned short* __restrict__ KV) {
  const int base = blockIdx.x * 2048 + threadIdx.x;
  for (int it = 0; it < 8; ++it) {
    int id = base + it * 256;  // (b, d, lc)
    int b = id >> 16, d = (id >> 8) & 255, lc = id & 255;
    ushort8 v = *(const ushort8*)(VT + ((size_t)(b * 256 + d)) * LL + lc * 8);
    int tile = b * 64 + (lc >> 2), c2 = lc & 3;
    *(ushort8*)(KV + (size_t)tile * TILE_U16 + KT_U16 + d * 32 + c2 * 8) = v;
  }
}

// ---------------------------------------------------------------------------
// Kernel 2: flash attention.  block 256 = 4 waves x 32 q-rows (q-tile 128),
// kv 32/iter via DMA double-buffer, 4-way kv split over blockIdx.z.
// grid (16,8,4) = 512 blocks = 2/CU, 8 waves/CU.
// ---------------------------------------------------------------------------
__global__ __launch_bounds__(256, 2) void attn(
    const unsigned short* __restrict__ Qb, const unsigned short* __restrict__ KV,
    const int* __restrict__ lens, float* __restrict__ out,
    unsigned short* __restrict__ p2, unsigned short* __restrict__ p3,
    float* __restrict__ ml) {
  // [0, 67584): 2 x KV tile (dbuf)   [67584, 77824): Ps 4 waves x 32 x 40 u16
  __shared__ __attribute__((aligned(16))) unsigned char smem[77824];
  const int t = threadIdx.x;
  const int wave = t >> 6, lane = t & 63, quad = lane >> 4, m16 = lane & 15;
  const int b = blockIdx.y, z = blockIdx.z;
  const int q0 = blockIdx.x * 128;
  const int len = lens[b];
  const int lo = z << 9;
  const int hi = min(len, lo + 512);
  const int T = (hi > lo) ? ((hi - lo + 31) >> 5) : 0;
  const size_t base = (size_t)b * LL * DD;

  half8 qf[2][8];
  for (int mt = 0; mt < 2; ++mt) {
    const unsigned short* qrow =
        Qb + base + (size_t)(q0 + wave * 32 + mt * 16 + m16) * DD + quad * 8;
    for (int kb = 0; kb < 8; ++kb)
      qf[mt][kb] = __builtin_bit_cast(half8, *(const ushort8*)(qrow + kb * 32));
  }

  floatx4 O[2][16];
  for (int mt = 0; mt < 2; ++mt)
    for (int i = 0; i < 16; ++i) O[mt][i] = (floatx4){0, 0, 0, 0};
  float mrow[2][4], lrow[2][4];
  for (int mt = 0; mt < 2; ++mt)
    for (int r = 0; r < 4; ++r) { mrow[mt][r] = -1e30f; lrow[mt][r] = 0.f; }

  const char* kvb = (const char*)KV + (size_t)(b * 64 + z * 16) * TILE_B;
  unsigned short* Pw = (unsigned short*)(smem + 67584) + wave * 1280;

  auto prefetch = [&](int it, int bufi) {
    const char* g = kvb + (size_t)it * TILE_B + lane * 16;
    char* l = (char*)smem + bufi * TILE_B;
    for (int c = wave; c < 33; c += 4) gll(g + c * 1024, l + c * 1024);
  };

  if (T) prefetch(0, 0);

  for (int it = 0; it < T; ++it) {
    __syncthreads();  // drains this buf's DMA; protects other buf for rewrite
    if (it + 1 < T) prefetch(it + 1, (it + 1) & 1);  // overlaps compute below
    const unsigned short* Ks = (const unsigned short*)(smem + (it & 1) * TILE_B);
    const unsigned short* Vs = Ks + KT_U16;
    const int kvq = lo + it * 32;

    // S = Q K^T : 2 mt x 2 n x 8 k (kf shared across mt)
    floatx4 s[2][2];
    for (int mt = 0; mt < 2; ++mt)
      for (int n = 0; n < 2; ++n) s[mt][n] = (floatx4){0, 0, 0, 0};
    for (int kb = 0; kb < 8; ++kb)
      for (int n = 0; n < 2; ++n) {
        half8 kf = __builtin_bit_cast(
            half8, *(const ushort8*)&Ks[(n * 16 + m16) * 272 +
                                        (((kb * 4 + quad) ^ (m16 & 7)) * 8)]);
        s[0][n] = __builtin_amdgcn_mfma_f32_16x16x32_f16(qf[0][kb], kf, s[0][n], 0, 0, 0);
        s[1][n] = __builtin_amdgcn_mfma_f32_16x16x32_f16(qf[1][kb], kf, s[1][n], 0, 0, 0);
      }
    // scale + mask + online softmax
    bool moved = false;
    float al[2][4];
    for (int mt = 0; mt < 2; ++mt) {
      for (int n = 0; n < 2; ++n) {
        bool valid = (kvq + n * 16 + m16) < hi;
        for (int r = 0; r < 4; ++r)
          s[mt][n][r] = valid ? s[mt][n][r] * 0.0625f : -1e30f;
      }
      for (int r = 0; r < 4; ++r) {
        float v = fmaxf(s[mt][0][r], s[mt][1][r]);
        v = fmaxf(v, __shfl_xor(v, 1));
        v = fmaxf(v, __shfl_xor(v, 2));
        v = fmaxf(v, __shfl_xor(v, 4));
        v = fmaxf(v, __shfl_xor(v, 8));
        float mn = fmaxf(mrow[mt][r], v);
        al[mt][r] = __expf(mrow[mt][r] - mn);
        mrow[mt][r] = mn;
        moved |= (al[mt][r] != 1.f);
        float sum = 0.f;
        for (int n = 0; n < 2; ++n) {
          float p = __expf(s[mt][n][r] - mn);
          Pw[(mt * 16 + quad * 4 + r) * 40 + n * 16 + m16] = f2h(p);
          sum += p;
        }
        sum += __shfl_xor(sum, 1);
        sum += __shfl_xor(sum, 2);
        sum += __shfl_xor(sum, 4);
        sum += __shfl_xor(sum, 8);
        lrow[mt][r] = lrow[mt][r] * al[mt][r] + sum;
      }
    }
    if (__ballot(moved)) {
      for (int mt = 0; mt < 2; ++mt)
        for (int i = 0; i < 16; ++i)
          for (int r = 0; r < 4; ++r) O[mt][i][r] *= al[mt][r];
    }
    // PV: vf shared across mt
    half8 pf0 = __builtin_bit_cast(half8,
                                   *(const ushort8*)&Pw[m16 * 40 + quad * 8]);
    half8 pf1 = __builtin_bit_cast(
        half8, *(const ushort8*)&Pw[(16 + m16) * 40 + quad * 8]);
    for (int nb = 0; nb < 16; ++nb) {
      half8 vf = __builtin_bit_cast(
          half8, *(const ushort8*)&Vs[(nb * 16 + m16) * 32 + quad * 8]);
      O[0][nb] = __builtin_amdgcn_mfma_f32_16x16x32_f16(pf0, vf, O[0][nb], 0, 0, 0);
      O[1][nb] = __builtin_amdgcn_mfma_f32_16x16x32_f16(pf1, vf, O[1][nb], 0, 0, 0);
    }
  }

  // epilogue: normalized f16 partial to part-slot; m,l to ws
  unsigned short* o16 = (unsigned short*)out;
  float inv[2][4];
  for (int mt = 0; mt < 2; ++mt)
    for (int r = 0; r < 4; ++r)
      inv[mt][r] = (lrow[mt][r] > 0.f) ? 1.f / lrow[mt][r] : 0.f;
  for (int mt = 0; mt < 2; ++mt)
    for (int nb = 0; nb < 16; ++nb)
      for (int r = 0; r < 4; ++r) {
        size_t idx = base +
                     (size_t)(q0 + wave * 32 + mt * 16 + quad * 4 + r) * DD +
                     nb * 16 + m16;
        unsigned short h = f2h(O[mt][nb][r] * inv[mt][r]);
        if (z == 0) o16[idx * 2] = h;
        else if (z == 1) o16[idx * 2 + 1] = h;
        else if (z == 2) p2[idx] = h;
        else p3[idx] = h;
      }
  if (m16 == 0)
    for (int mt = 0; mt < 2; ++mt)
      for (int r = 0; r < 4; ++r) {
        int rid = b * LL + q0 + wave * 32 + mt * 16 + quad * 4 + r;
        ml[(z * (BB * LL) + rid) * 2] = mrow[mt][r];
        ml[(z * (BB * LL) + rid) * 2 + 1] = lrow[mt][r];
      }
}

// ---------------------------------------------------------------------------
// Kernel 3: 4-way merge.  grid 1024, block 256.
// ---------------------------------------------------------------------------
__global__ __launch_bounds__(256) void merge(
    float* __restrict__ out, const unsigned short* __restrict__ p2,
    const unsigned short* __restrict__ p3, const float* __restrict__ ml) {
  const int tg = blockIdx.x * 256 + threadIdx.x;
  for (int j = 0; j < 4; ++j) {
    int qid = j * 262144 + tg;  // f32x4 quads over 16384x256
    int row = qid >> 6;
    float m0 = ml[row * 2], l0 = ml[row * 2 + 1];
    float m1 = ml[(BB * LL + row) * 2], l1 = ml[(BB * LL + row) * 2 + 1];
    float m2 = ml[(2 * BB * LL + row) * 2], l2 = ml[(2 * BB * LL + row) * 2 + 1];
    float m3 = ml[(3 * BB * LL + row) * 2], l3 = ml[(3 * BB * LL + row) * 2 + 1];
    float m = fmaxf(fmaxf(m0, m1), fmaxf(m2, m3));
    float w0 = l0 * __expf(m0 - m), w1 = l1 * __expf(m1 - m);
    float w2 = l2 * __expf(m2 - m), w3 = l3 * __expf(m3 - m);
    float inv = 1.f / (w0 + w1 + w2 + w3);
    w0 *= inv; w1 *= inv; w2 *= inv; w3 *= inv;
    uint4 u01 = ((const uint4*)out)[qid];
    ushort4v u2 = ((const ushort4v*)p2)[qid];
    ushort4v u3 = ((const ushort4v*)p3)[qid];
    float4 o;
    o.x = h2f16((unsigned short)u01.x) * w0 + h2f16((unsigned short)(u01.x >> 16)) * w1 +
          h2f16(u2[0]) * w2 + h2f16(u3[0]) * w3;
    o.y = h2f16((unsigned short)u01.y) * w0 + h2f16((unsigned short)(u01.y >> 16)) * w1 +
          h2f16(u2[1]) * w2 + h2f16(u3[1]) * w3;
    o.z = h2f16((unsigned short)u01.z) * w0 + h2f16((unsigned short)(u01.z >> 16)) * w1 +
          h2f16(u2[2]) * w2 + h2f16(u3[2]) * w3;
    o.w = h2f16((unsigned short)u01.w) * w0 + h2f16((unsigned short)(u01.w >> 16)) * w1 +
          h2f16(u2[3]) * w2 + h2f16(u3[3]) * w3;
    ((float4*)out)[qid] = o;
  }
}

extern "C" void kernel_launch(void* const* d_in, const int* in_sizes, int n_in,
                              void* d_out, int out_size, void* d_ws, size_t ws_size,
                              hipStream_t stream) {
  const float* x = (const float*)d_in[0];
  const float* Wq = (const float*)d_in[1];
  const float* Wk = (const float*)d_in[2];
  const float* Wv = (const float*)d_in[3];
  const int* lens = (const int*)d_in[4];
  unsigned short* Qb = (unsigned short*)d_ws;
  unsigned short* Kb = Qb + (size_t)BB * LL * DD;    // later reused as p2
  unsigned short* VT = Kb + (size_t)BB * LL * DD;    // later reused as p3
  unsigned short* KV = VT + (size_t)BB * LL * DD;    // 512 tiles
  float* ml = (float*)(KV + (size_t)BB * 64 * TILE_U16);
  float* out = (float*)d_out;

  qk_proj<<<dim3(256, 2), 256, 0, stream>>>(x, Wq, Wk, Qb, Kb);
  vproj_t<<<dim3(256), 256, 0, stream>>>(x, Wv, VT);
  kpack<<<256, 256, 0, stream>>>(Kb, KV);
  vpack<<<256, 256, 0, stream>>>(VT, KV);
  attn<<<dim3(16, 8, 4), 256, 0, stream>>>(Qb, KV, lens, out, Kb, VT, ml);
  merge<<<1024, 256, 0, stream>>>(out, Kb, VT, ml);
}

// Round 8
// 199.519 us; speedup vs baseline: 2.2194x; 2.2194x over previous
//
#include <hip/hip_runtime.h>

#define BB 8
#define LL 2048
#define DD 256
// KV image tile = 32 kv rows:
//   K part: 32 rows x 272 u16, 16B chunk c of row rr stored at c^(rr&7)
//   V part: 256 d x 32 kv u16 (aligned, conflict-free at stride 32)
#define KT_U16 8704
#define TILE_U16 16896
#define TILE_B 33792

typedef _Float16 half8 __attribute__((ext_vector_type(8)));
typedef float floatx4 __attribute__((ext_vector_type(4)));
typedef unsigned short ushort8 __attribute__((ext_vector_type(8)));
typedef unsigned short ushort4v __attribute__((ext_vector_type(4)));

__device__ inline unsigned short f2h(float f) {
  _Float16 h = (_Float16)f;
  return __builtin_bit_cast(unsigned short, h);
}
__device__ inline float h2f16(unsigned short v) {
  return (float)__builtin_bit_cast(_Float16, v);
}

__device__ inline void gll(const void* g, void* l) {
  __builtin_amdgcn_global_load_lds(
      (const __attribute__((address_space(1))) unsigned int*)g,
      (__attribute__((address_space(3))) unsigned int*)l, 16, 0, 0);
}

// ---------------------------------------------------------------------------
// Kernel 1: Q/K projection (R2-proven).  Out[l][d] fp16.
// ---------------------------------------------------------------------------
__global__ __launch_bounds__(256) void qk_proj(
    const float* __restrict__ x,
    const float* __restrict__ Wq, const float* __restrict__ Wk,
    unsigned short* __restrict__ Qb, unsigned short* __restrict__ Kb) {
  __shared__ __attribute__((aligned(16))) unsigned short Xs[64 * 264];
  __shared__ __attribute__((aligned(16))) unsigned short Ws[32 * 264];
  const int t = threadIdx.x;
  const int wave = t >> 6, lane = t & 63, quad = lane >> 4, m16 = lane & 15;
  const int r0 = blockIdx.x * 64;
  const float* W = (blockIdx.y == 0) ? Wq : Wk;
  unsigned short* Out = (blockIdx.y == 0) ? Qb : Kb;

  for (int p = 0; p < 16; ++p) {
    int idx = p * 1024 + t * 4;
    int row = idx >> 8, col = idx & 255;
    float4 v = *(const float4*)(x + (size_t)(r0 + row) * DD + col);
    ushort4v h = {f2h(v.x), f2h(v.y), f2h(v.z), f2h(v.w)};
    *(ushort4v*)&Xs[row * 264 + col] = h;
  }
  __syncthreads();

  half8 af[8];
  for (int kb = 0; kb < 8; ++kb)
    af[kb] = __builtin_bit_cast(
        half8, *(const ushort8*)&Xs[(wave * 16 + m16) * 264 + kb * 32 + quad * 8]);

  for (int c = 0; c < 8; ++c) {
    if (c) __syncthreads();
    for (int p = 0; p < 8; ++p) {
      int idx = p * 1024 + t * 4;
      int row = idx >> 8, col = idx & 255;
      float4 v = *(const float4*)(W + (size_t)(c * 32 + row) * DD + col);
      ushort4v h = {f2h(v.x), f2h(v.y), f2h(v.z), f2h(v.w)};
      *(ushort4v*)&Ws[row * 264 + col] = h;
    }
    __syncthreads();
    floatx4 acc[2] = {{0, 0, 0, 0}, {0, 0, 0, 0}};
    for (int n = 0; n < 2; ++n)
      for (int kb = 0; kb < 8; ++kb) {
        half8 bf = __builtin_bit_cast(
            half8,
            *(const ushort8*)&Ws[(n * 16 + m16) * 264 + kb * 32 + quad * 8]);
        acc[n] = __builtin_amdgcn_mfma_f32_16x16x32_f16(af[kb], bf, acc[n], 0, 0, 0);
      }
    for (int n = 0; n < 2; ++n)
      for (int r = 0; r < 4; ++r) {
        int rowg = r0 + wave * 16 + quad * 4 + r;
        int colg = c * 32 + n * 16 + m16;
        Out[(size_t)rowg * DD + colg] = f2h(acc[n][r]);
      }
  }
}

// ---------------------------------------------------------------------------
// Kernel 1b: V projection writing V TRANSPOSED VT[b][d][l] (R2-proven).
// ---------------------------------------------------------------------------
__global__ __launch_bounds__(256) void vproj_t(
    const float* __restrict__ x, const float* __restrict__ Wv,
    unsigned short* __restrict__ VT) {
  __shared__ __attribute__((aligned(16))) unsigned short Xs[64 * 264];
  __shared__ __attribute__((aligned(16))) unsigned short Ws[64 * 264];
  const int t = threadIdx.x;
  const int wave = t >> 6, lane = t & 63, quad = lane >> 4, m16 = lane & 15;
  const int l0 = blockIdx.x * 64;
  const int b = l0 >> 11, lb = l0 & 2047;

  for (int p = 0; p < 16; ++p) {
    int idx = p * 1024 + t * 4;
    int row = idx >> 8, col = idx & 255;
    float4 v = *(const float4*)(x + (size_t)(l0 + row) * DD + col);
    ushort4v h = {f2h(v.x), f2h(v.y), f2h(v.z), f2h(v.w)};
    *(ushort4v*)&Xs[row * 264 + col] = h;
  }
  __syncthreads();

  half8 xf[8];
  for (int kb = 0; kb < 8; ++kb)
    xf[kb] = __builtin_bit_cast(
        half8, *(const ushort8*)&Xs[(wave * 16 + m16) * 264 + kb * 32 + quad * 8]);

  for (int c = 0; c < 4; ++c) {
    if (c) __syncthreads();
    for (int p = 0; p < 16; ++p) {
      int idx = p * 1024 + t * 4;
      int row = idx >> 8, col = idx & 255;
      float4 v = *(const float4*)(Wv + (size_t)(c * 64 + row) * DD + col);
      ushort4v h = {f2h(v.x), f2h(v.y), f2h(v.z), f2h(v.w)};
      *(ushort4v*)&Ws[row * 264 + col] = h;
    }
    __syncthreads();
    for (int mt = 0; mt < 4; ++mt) {
      floatx4 acc = {0, 0, 0, 0};
      for (int kb = 0; kb < 8; ++kb) {
        half8 af = __builtin_bit_cast(
            half8,
            *(const ushort8*)&Ws[(mt * 16 + m16) * 264 + kb * 32 + quad * 8]);
        acc = __builtin_amdgcn_mfma_f32_16x16x32_f16(af, xf[kb], acc, 0, 0, 0);
      }
      int o = c * 64 + mt * 16 + quad * 4;
      int l = lb + wave * 16 + m16;
      for (int r = 0; r < 4; ++r)
        VT[((size_t)(b * DD + o + r)) * LL + l] = f2h(acc[r]);
    }
  }
}

// ---------------------------------------------------------------------------
// Kernel 1c: pack Kb[l][d] -> swizzled K part of KV image.
// ---------------------------------------------------------------------------
__global__ __launch_bounds__(256) void kpack(
    const unsigned short* __restrict__ Kb, unsigned short* __restrict__ KV) {
  const int base = blockIdx.x * 2048 + threadIdx.x;
  for (int it = 0; it < 8; ++it) {
    int id = base + it * 256;
    int row = id >> 5, c = id & 31;
    ushort8 v = *(const ushort8*)(Kb + (size_t)row * DD + c * 8);
    int tile = row >> 5, rr = row & 31;
    *(ushort8*)(KV + (size_t)tile * TILE_U16 + rr * 272 + ((c ^ (rr & 7)) * 8)) = v;
  }
}

// ---------------------------------------------------------------------------
// Kernel 1d: pack VT[b][d][l] -> V part of KV image ([d][32kv] per tile).
// ---------------------------------------------------------------------------
__global__ __launch_bounds__(256) void vpack(
    const unsigned short* __restrict__ VT, unsigned short* __restrict__ KV) {
  const int base = blockIdx.x * 2048 + threadIdx.x;
  for (int it = 0; it < 8; ++it) {
    int id = base + it * 256;
    int b = id >> 16, d = (id >> 8) & 255, lc = id & 255;
    ushort8 v = *(const ushort8*)(VT + ((size_t)(b * 256 + d)) * LL + lc * 8);
    int tile = b * 64 + (lc >> 2), c2 = lc & 3;
    *(ushort8*)(KV + (size_t)tile * TILE_U16 + KT_U16 + d * 32 + c2 * 8) = v;
  }
}

// ---------------------------------------------------------------------------
// Kernel 2: flash attention.  block 256 = 4 waves x 32 q-rows (q-tile 128),
// kv 32/iter via DMA double-buffer, 4-way kv split over blockIdx.z.
// grid (16,8,4) = 512 blocks = 2/CU, 8 waves/CU.
// Partials: f16, 32B slice-interleaved; slices 0/1 in d_out, 2/3 in p23 ws.
// ---------------------------------------------------------------------------
__global__ __launch_bounds__(256, 2) void attn(
    const unsigned short* __restrict__ Qb, const unsigned short* __restrict__ KV,
    const int* __restrict__ lens, float* __restrict__ out,
    unsigned short* __restrict__ p23, float* __restrict__ ml) {
  // [0, 67584): 2 x KV tile (dbuf); reused as epilogue tile [128][264]
  // [67584, 77824): Ps 4 waves x 32 x 40 u16
  __shared__ __attribute__((aligned(16))) unsigned char smem[77824];
  const int t = threadIdx.x;
  const int wave = t >> 6, lane = t & 63, quad = lane >> 4, m16 = lane & 15;
  const int b = blockIdx.y, z = blockIdx.z;
  const int q0 = blockIdx.x * 128;
  const int len = lens[b];
  const int lo = z << 9;
  const int hi = min(len, lo + 512);
  const int T = (hi > lo) ? ((hi - lo + 31) >> 5) : 0;
  const size_t base = (size_t)b * LL * DD;

  half8 qf[2][8];
  for (int mt = 0; mt < 2; ++mt) {
    const unsigned short* qrow =
        Qb + base + (size_t)(q0 + wave * 32 + mt * 16 + m16) * DD + quad * 8;
    for (int kb = 0; kb < 8; ++kb)
      qf[mt][kb] = __builtin_bit_cast(half8, *(const ushort8*)(qrow + kb * 32));
  }

  floatx4 O[2][16];
  for (int mt = 0; mt < 2; ++mt)
    for (int i = 0; i < 16; ++i) O[mt][i] = (floatx4){0, 0, 0, 0};
  float mrow[2][4], lrow[2][4];
  for (int mt = 0; mt < 2; ++mt)
    for (int r = 0; r < 4; ++r) { mrow[mt][r] = -1e30f; lrow[mt][r] = 0.f; }

  const char* kvb = (const char*)KV + (size_t)(b * 64 + z * 16) * TILE_B;
  unsigned short* Pw = (unsigned short*)(smem + 67584) + wave * 1280;

  auto prefetch = [&](int it, int bufi) {
    const char* g = kvb + (size_t)it * TILE_B + lane * 16;
    char* l = (char*)smem + bufi * TILE_B;
    for (int c = wave; c < 33; c += 4) gll(g + c * 1024, l + c * 1024);
  };

  if (T) prefetch(0, 0);

  for (int it = 0; it < T; ++it) {
    __syncthreads();  // drains this buf's DMA; other buf safe to rewrite
    if (it + 1 < T) prefetch(it + 1, (it + 1) & 1);  // overlaps compute below
    const unsigned short* Ks = (const unsigned short*)(smem + (it & 1) * TILE_B);
    const unsigned short* Vs = Ks + KT_U16;
    const int kvq = lo + it * 32;

    // S = Q K^T : 2 mt x 2 n x 8 k (kf shared across mt)
    floatx4 s[2][2];
    for (int mt = 0; mt < 2; ++mt)
      for (int n = 0; n < 2; ++n) s[mt][n] = (floatx4){0, 0, 0, 0};
    for (int kb = 0; kb < 8; ++kb)
      for (int n = 0; n < 2; ++n) {
        half8 kf = __builtin_bit_cast(
            half8, *(const ushort8*)&Ks[(n * 16 + m16) * 272 +
                                        (((kb * 4 + quad) ^ (m16 & 7)) * 8)]);
        s[0][n] = __builtin_amdgcn_mfma_f32_16x16x32_f16(qf[0][kb], kf, s[0][n], 0, 0, 0);
        s[1][n] = __builtin_amdgcn_mfma_f32_16x16x32_f16(qf[1][kb], kf, s[1][n], 0, 0, 0);
      }
    // scale + mask + online softmax
    bool moved = false;
    float al[2][4];
    for (int mt = 0; mt < 2; ++mt) {
      for (int n = 0; n < 2; ++n) {
        bool valid = (kvq + n * 16 + m16) < hi;
        for (int r = 0; r < 4; ++r)
          s[mt][n][r] = valid ? s[mt][n][r] * 0.0625f : -1e30f;
      }
      for (int r = 0; r < 4; ++r) {
        float v = fmaxf(s[mt][0][r], s[mt][1][r]);
        v = fmaxf(v, __shfl_xor(v, 1));
        v = fmaxf(v, __shfl_xor(v, 2));
        v = fmaxf(v, __shfl_xor(v, 4));
        v = fmaxf(v, __shfl_xor(v, 8));
        float mn = fmaxf(mrow[mt][r], v);
        al[mt][r] = __expf(mrow[mt][r] - mn);
        mrow[mt][r] = mn;
        moved |= (al[mt][r] != 1.f);
        float sum = 0.f;
        for (int n = 0; n < 2; ++n) {
          float p = __expf(s[mt][n][r] - mn);
          Pw[(mt * 16 + quad * 4 + r) * 40 + n * 16 + m16] = f2h(p);
          sum += p;
        }
        sum += __shfl_xor(sum, 1);
        sum += __shfl_xor(sum, 2);
        sum += __shfl_xor(sum, 4);
        sum += __shfl_xor(sum, 8);
        lrow[mt][r] = lrow[mt][r] * al[mt][r] + sum;
      }
    }
    if (__ballot(moved)) {
      for (int mt = 0; mt < 2; ++mt)
        for (int i = 0; i < 16; ++i)
          for (int r = 0; r < 4; ++r) O[mt][i][r] *= al[mt][r];
    }
    // PV: vf shared across mt
    half8 pf0 = __builtin_bit_cast(half8,
                                   *(const ushort8*)&Pw[m16 * 40 + quad * 8]);
    half8 pf1 = __builtin_bit_cast(
        half8, *(const ushort8*)&Pw[(16 + m16) * 40 + quad * 8]);
    for (int nb = 0; nb < 16; ++nb) {
      half8 vf = __builtin_bit_cast(
          half8, *(const ushort8*)&Vs[(nb * 16 + m16) * 32 + quad * 8]);
      O[0][nb] = __builtin_amdgcn_mfma_f32_16x16x32_f16(pf0, vf, O[0][nb], 0, 0, 0);
      O[1][nb] = __builtin_amdgcn_mfma_f32_16x16x32_f16(pf1, vf, O[1][nb], 0, 0, 0);
    }
  }

  // ---- epilogue: normalized f16 partial via LDS transpose, WIDE stores ----
  __syncthreads();  // all LDS (dbuf) reads done; safe to reuse as Eo
  unsigned short* Eo = (unsigned short*)smem;  // [128][264]
  float inv[2][4];
  for (int mt = 0; mt < 2; ++mt)
    for (int r = 0; r < 4; ++r)
      inv[mt][r] = (lrow[mt][r] > 0.f) ? 1.f / lrow[mt][r] : 0.f;
  for (int mt = 0; mt < 2; ++mt)
    for (int nb = 0; nb < 16; ++nb)
      for (int r = 0; r < 4; ++r)
        Eo[(wave * 32 + mt * 16 + quad * 4 + r) * 264 + nb * 16 + m16] =
            f2h(O[mt][nb][r] * inv[mt][r]);
  __syncthreads();
  // 32B slice-interleave: u16 addr = row_g*512 + c16*32 + slice*16 + w
  unsigned short* obase = (z < 2) ? (unsigned short*)out : p23;
  const int zz = z & 1;
  const size_t rg0 = (size_t)b * LL + q0;
  for (int i = 0; i < 16; ++i) {
    int hc = t + i * 256;  // 4096 half-chunks of 8 u16
    int row = hc >> 5, col8 = hc & 31;
    ushort8 v = *(const ushort8*)&Eo[row * 264 + col8 * 8];
    *(ushort8*)(obase + (rg0 + row) * 512 + (col8 >> 1) * 32 + zz * 16 +
                (col8 & 1) * 8) = v;
  }
  if (m16 == 0)
    for (int mt = 0; mt < 2; ++mt)
      for (int r = 0; r < 4; ++r) {
        int rid = b * LL + q0 + wave * 32 + mt * 16 + quad * 4 + r;
        ml[(z * (BB * LL) + rid) * 2] = mrow[mt][r];
        ml[(z * (BB * LL) + rid) * 2 + 1] = lrow[mt][r];
      }
}

// ---------------------------------------------------------------------------
// Kernel 3: 4-way merge, fully wide & race-free (thread reads exactly the
// 64B of d_out it overwrites).  grid 1024, block 256.
// ---------------------------------------------------------------------------
__global__ __launch_bounds__(256) void merge(
    float* __restrict__ out, const unsigned short* __restrict__ p23,
    const float* __restrict__ ml) {
  const int k = blockIdx.x * 256 + threadIdx.x;  // 262144 chunks of 16 outputs
  const int row = k >> 4;
  float m0 = ml[row * 2], l0 = ml[row * 2 + 1];
  float m1 = ml[(BB * LL + row) * 2], l1 = ml[(BB * LL + row) * 2 + 1];
  float m2 = ml[(2 * BB * LL + row) * 2], l2 = ml[(2 * BB * LL + row) * 2 + 1];
  float m3 = ml[(3 * BB * LL + row) * 2], l3 = ml[(3 * BB * LL + row) * 2 + 1];
  float m = fmaxf(fmaxf(m0, m1), fmaxf(m2, m3));
  float w0 = l0 * __expf(m0 - m), w1 = l1 * __expf(m1 - m);
  float w2 = l2 * __expf(m2 - m), w3 = l3 * __expf(m3 - m);
  float inv = 1.f / (w0 + w1 + w2 + w3);
  w0 *= inv; w1 *= inv; w2 *= inv; w3 *= inv;
  ushort8 a0 = ((const ushort8*)out)[k * 4 + 0];
  ushort8 a1 = ((const ushort8*)out)[k * 4 + 1];
  ushort8 b0 = ((const ushort8*)out)[k * 4 + 2];
  ushort8 b1 = ((const ushort8*)out)[k * 4 + 3];
  ushort8 c0 = ((const ushort8*)p23)[k * 4 + 0];
  ushort8 c1 = ((const ushort8*)p23)[k * 4 + 1];
  ushort8 d0 = ((const ushort8*)p23)[k * 4 + 2];
  ushort8 d1 = ((const ushort8*)p23)[k * 4 + 3];
  float o[16];
  for (int j = 0; j < 8; ++j)
    o[j] = h2f16(a0[j]) * w0 + h2f16(b0[j]) * w1 + h2f16(c0[j]) * w2 +
           h2f16(d0[j]) * w3;
  for (int j = 0; j < 8; ++j)
    o[8 + j] = h2f16(a1[j]) * w0 + h2f16(b1[j]) * w1 + h2f16(c1[j]) * w2 +
               h2f16(d1[j]) * w3;
  for (int q = 0; q < 4; ++q)
    ((float4*)out)[k * 4 + q] = *(float4*)&o[q * 4];
}

extern "C" void kernel_launch(void* const* d_in, const int* in_sizes, int n_in,
                              void* d_out, int out_size, void* d_ws, size_t ws_size,
                              hipStream_t stream) {
  const float* x = (const float*)d_in[0];
  const float* Wq = (const float*)d_in[1];
  const float* Wk = (const float*)d_in[2];
  const float* Wv = (const float*)d_in[3];
  const int* lens = (const int*)d_in[4];
  unsigned short* Qb = (unsigned short*)d_ws;
  unsigned short* Kb = Qb + (size_t)BB * LL * DD;  // reused as p23 (with VT)
  unsigned short* VT = Kb + (size_t)BB * LL * DD;
  unsigned short* KV = VT + (size_t)BB * LL * DD;
  float* ml = (float*)(KV + (size_t)BB * 64 * TILE_U16);
  float* out = (float*)d_out;

  qk_proj<<<dim3(256, 2), 256, 0, stream>>>(x, Wq, Wk, Qb, Kb);
  vproj_t<<<dim3(256), 256, 0, stream>>>(x, Wv, VT);
  kpack<<<256, 256, 0, stream>>>(Kb, KV);
  vpack<<<256, 256, 0, stream>>>(VT, KV);
  attn<<<dim3(16, 8, 4), 256, 0, stream>>>(Qb, KV, lens, out, Kb, ml);
  merge<<<1024, 256, 0, stream>>>(out, Kb, ml);
}